// Round 7
// baseline (176.786 us; speedup 1.0000x reference)
//
#include <hip/hip_runtime.h>
#include <hip/hip_bf16.h>

// Problem constants (QREncoder: path signature depth 4 + linear head)
#define BATCH 64
#define LSEQ 256
#define CIN 7
#define CC 8           // channels incl. time
#define NSIG 4680      // 8 + 64 + 512 + 4096
#define KPAD 4736      // NSIG padded to multiple of 64
#define TSTEPS 255     // LSEQ - 1
#define ODIM 512
#define NCHUNK 16      // time chunks for sig write parallelism
#define CH 16          // steps per chunk (last chunk: 15)
#define NKT 74         // KPAD / 64 K-steps
#define BM 256
#define BN 128

typedef __attribute__((ext_vector_type(8))) unsigned short ushort8;
typedef __attribute__((ext_vector_type(8))) __bf16 bf16x8;
typedef __attribute__((ext_vector_type(4))) float f32x4;

__device__ __forceinline__ unsigned short f2bf(float x) {
    __hip_bfloat16 h = __float2bfloat16(x);   // RNE
    return *(unsigned short*)&h;
}

#define GLDS16(gp, lp)                                                      \
    __builtin_amdgcn_global_load_lds(                                       \
        (const __attribute__((address_space(1))) void*)(gp),                \
        (__attribute__((address_space(3))) void*)(lp), 16, 0, 0)

// ---------------------------------------------------------------------------
// Scan pass A: one block per batch, sequential 255-step state-only scan,
// dumping full state (4680 f32) at t = 16,32,...,240 (15 checkpoints).
// ---------------------------------------------------------------------------
__global__ __launch_bounds__(512) void sig_ckpt_kernel(const float* __restrict__ inp,
                                                       float* __restrict__ ckpt) {
    __shared__ float sDx[TSTEPS * CC];

    const int b   = blockIdx.x;
    const int tid = threadIdx.x;

    const float* ip = inp + (size_t)b * LSEQ * CIN;
    for (int i = tid; i < TSTEPS * CC; i += 512) {
        int t = i >> 3, c = i & 7;
        sDx[i] = (c == 0) ? (1.0f / 255.0f)
                          : ip[(t + 1) * CIN + (c - 1)] - ip[t * CIN + (c - 1)];
    }
    __syncthreads();

    const int i1 = tid >> 6;
    const int i2 = (tid >> 3) & 7;
    const int i3 = tid & 7;

    float a1own = 0.0f, a2own = 0.0f, a3 = 0.0f;
    float a4[8];
#pragma unroll
    for (int e = 0; e < 8; ++e) a4[e] = 0.0f;

    for (int t = 0; t < 240; ++t) {
        const float* v = &sDx[t * CC];
        const float4 vlo = *(const float4*)&v[0];
        const float4 vhi = *(const float4*)&v[4];
        const float va = v[i1], vb = v[i2], vc = v[i3];
        const float e3s = va * vb * vc * (1.0f / 6.0f);
        const float T4 = e3s * 0.25f + a1own * vb * vc * (1.0f / 6.0f)
                       + a2own * vc * 0.5f + a3;
        a4[0] += vlo.x * T4; a4[1] += vlo.y * T4;
        a4[2] += vlo.z * T4; a4[3] += vlo.w * T4;
        a4[4] += vhi.x * T4; a4[5] += vhi.y * T4;
        a4[6] += vhi.z * T4; a4[7] += vhi.w * T4;
        a3 += e3s + (a1own * vb * 0.5f + a2own) * vc;
        a2own += vb * (0.5f * va + a1own);
        a1own += va;

        if (((t + 1) & 15) == 0) {            // t+1 in {16,...,240}
            const int c = ((t + 1) >> 4) - 1; // 0..14
            float* cp = ckpt + ((size_t)b * 15 + c) * NSIG;
            if ((tid & 63) == 0) cp[i1] = a1own;
            if ((tid & 7) == 0) cp[8 + (tid >> 3)] = a2own;
            cp[72 + tid] = a3;
            float4 q0 = {a4[0], a4[1], a4[2], a4[3]};
            float4 q1 = {a4[4], a4[5], a4[6], a4[7]};
            *(float4*)&cp[584 + tid * 8]     = q0;
            *(float4*)&cp[584 + tid * 8 + 4] = q1;
        }
    }
}

// ---------------------------------------------------------------------------
// Scan pass B: grid (NCHUNK, nb). Block (chunk,b) loads the chunk's start
// state from ckpt (chunk 0: zeros), runs <=16 steps, writes sig rows (bf16).
// ---------------------------------------------------------------------------
__global__ __launch_bounds__(512) void sig_write_kernel(const float* __restrict__ inp,
                                                        const float* __restrict__ ckpt,
                                                        unsigned short* __restrict__ sig) {
    __shared__ float sDx[CH * CC];

    const int chunk = blockIdx.x;
    const int b     = blockIdx.y;
    const int tid   = threadIdx.x;
    const int t0    = chunk * CH;
    const int t1    = (chunk == NCHUNK - 1) ? TSTEPS : t0 + CH;

    const float* ip = inp + (size_t)b * LSEQ * CIN;
    for (int i = tid; i < (t1 - t0) * CC; i += 512) {
        int t = t0 + (i >> 3), c = i & 7;
        sDx[i] = (c == 0) ? (1.0f / 255.0f)
                          : ip[(t + 1) * CIN + (c - 1)] - ip[t * CIN + (c - 1)];
    }
    __syncthreads();

    const int i1 = tid >> 6;
    const int i2 = (tid >> 3) & 7;
    const int i3 = tid & 7;

    float a1own, a2own, a3;
    float a4[8];
    if (chunk == 0) {
        a1own = a2own = a3 = 0.0f;
#pragma unroll
        for (int e = 0; e < 8; ++e) a4[e] = 0.0f;
    } else {
        const float* cp = ckpt + ((size_t)b * 15 + (chunk - 1)) * NSIG;
        a1own = cp[i1];
        a2own = cp[8 + (tid >> 3)];
        a3    = cp[72 + tid];
        float4 q0 = *(const float4*)&cp[584 + tid * 8];
        float4 q1 = *(const float4*)&cp[584 + tid * 8 + 4];
        a4[0] = q0.x; a4[1] = q0.y; a4[2] = q0.z; a4[3] = q0.w;
        a4[4] = q1.x; a4[5] = q1.y; a4[6] = q1.z; a4[7] = q1.w;
    }

    for (int t = t0; t < t1; ++t) {
        const float* v = &sDx[(t - t0) * CC];
        const float4 vlo = *(const float4*)&v[0];
        const float4 vhi = *(const float4*)&v[4];
        const float va = v[i1], vb = v[i2], vc = v[i3];
        const float e3s = va * vb * vc * (1.0f / 6.0f);
        const float T4 = e3s * 0.25f + a1own * vb * vc * (1.0f / 6.0f)
                       + a2own * vc * 0.5f + a3;
        a4[0] += vlo.x * T4; a4[1] += vlo.y * T4;
        a4[2] += vlo.z * T4; a4[3] += vlo.w * T4;
        a4[4] += vhi.x * T4; a4[5] += vhi.y * T4;
        a4[6] += vhi.z * T4; a4[7] += vhi.w * T4;
        a3 += e3s + (a1own * vb * 0.5f + a2own) * vc;
        a2own += vb * (0.5f * va + a1own);
        a1own += va;

        unsigned short* row = sig + ((size_t)b * TSTEPS + t) * KPAD;
        ushort8 pack;
#pragma unroll
        for (int e = 0; e < 8; ++e) pack[e] = f2bf(a4[e]);
        *(ushort8*)(row + 584 + tid * 8) = pack;                // level 4
        row[72 + tid] = f2bf(a3);                               // level 3
        if ((tid & 63) == 0) row[i1] = f2bf(a1own);             // level 1
        if ((tid & 7) == 0) row[8 + (tid >> 3)] = f2bf(a2own);  // level 2
        if (tid >= 448 && tid < 504) row[4232 + tid] = 0;       // pad
    }
}

// ---------------------------------------------------------------------------
// W fp32 [512][4680] -> bf16 [512][KPAD] (pad zeroed)
// ---------------------------------------------------------------------------
__global__ __launch_bounds__(256) void wcvt_kernel(const float* __restrict__ W,
                                                   unsigned short* __restrict__ Wb) {
    int idx = blockIdx.x * 256 + threadIdx.x;
    if (idx >= ODIM * KPAD) return;
    int n = idx / KPAD, k = idx - n * KPAD;
    Wb[idx] = (k < NSIG) ? f2bf(W[(size_t)n * NSIG + k]) : (unsigned short)0;
}

// ---------------------------------------------------------------------------
// MFMA GEMM, depth-2 counted-vmcnt pipeline (T3/T4).
// BM=256 x BN=128 tile, BK=64, 8 waves (4Mx2N, each 64x64 of 4x4 16x16x32
// frags), 3 LDS buffers (144 KB) -> exactly 1 block/CU, grid = 64x4 = 256.
// Invariant at iter t: buf[t%3] ready, tile t+1 in flight (6 loads/thread).
// Iter: issue tile t+2 -> buf[(t+2)%3]; compute buf[t%3]; s_waitcnt vmcnt(6)
// (waits ONLY tile t+1; t+2 stays in flight across the barrier - never
// drain to 0 in the loop); raw s_barrier + sched_barrier fences.
// T2 XOR-swizzle as R5 (bank conflicts == 0). XCD-grouped block swizzle.
// ---------------------------------------------------------------------------
__global__ __launch_bounds__(512) void gemm_kernel(const unsigned short* __restrict__ A,
                                                   const unsigned short* __restrict__ Wb,
                                                   const float* __restrict__ bias,
                                                   float* __restrict__ out,
                                                   int Mrows) {
    __shared__ unsigned short As[3][BM * 64];   // 3 x 32 KB
    __shared__ unsigned short Bs[3][BN * 64];   // 3 x 16 KB

    const int tid = threadIdx.x;
    int nt, mt;
    if (gridDim.y == 64) {                     // full dispatch (256 blocks)
        const int li = blockIdx.y * 4 + blockIdx.x;
        const int x  = li & 7;                 // XCD (round-robin assumption)
        const int j  = li >> 3;                // 0..31 within XCD
        mt = x * 8 + (j >> 2);                 // 8 m-panels per XCD
        nt = j & 3;
    } else {
        nt = blockIdx.x; mt = blockIdx.y;
    }
    const int lane = tid & 63;
    const int wv   = tid >> 6;                 // 0..7
    const int wr   = wv >> 1;                  // 0..3 (M)
    const int wc   = wv & 1;                   // 0..1 (N)
    const int lr   = lane & 15;
    const int lk   = (lane >> 4) * 8;
    const int sb   = lr & 7;                   // read-side swizzle key

    const f32x4 z4 = {0.0f, 0.0f, 0.0f, 0.0f};
    f32x4 acc[4][4];
#pragma unroll
    for (int i = 0; i < 4; ++i)
#pragma unroll
        for (int j = 0; j < 4; ++j) acc[i][j] = z4;

    const int srow = tid >> 3;                          // 0..63
    const int gcb  = (tid & 7) ^ (srow & 7);            // pre-swizzled src blk
    const int scol = gcb * 8;

    // per-lane global source pointers (A rows clamped for M-tail)
    const unsigned short* aptr[4];
    const unsigned short* bptr[2];
#pragma unroll
    for (int i = 0; i < 4; ++i) {
        int gr = mt * BM + i * 64 + srow;
        if (gr >= Mrows) gr = 0;
        aptr[i] = A + (size_t)gr * KPAD + scol;
    }
#pragma unroll
    for (int i = 0; i < 2; ++i)
        bptr[i] = Wb + (size_t)(nt * BN + i * 64 + srow) * KPAD + scol;

#define STAGE(buf, koff)                                                    \
    do {                                                                    \
        _Pragma("unroll")                                                   \
        for (int i_ = 0; i_ < 4; ++i_)                                      \
            GLDS16(aptr[i_] + (koff),                                       \
                   ((char*)As[buf]) + i_ * 8192 + tid * 16);                \
        _Pragma("unroll")                                                   \
        for (int i_ = 0; i_ < 2; ++i_)                                      \
            GLDS16(bptr[i_] + (koff),                                       \
                   ((char*)Bs[buf]) + i_ * 8192 + tid * 16);                \
    } while (0)

    // prologue: tiles 0 and 1 in flight; wait tile 0 (vmcnt 6 = tile 1 stays)
    STAGE(0, 0);
    STAGE(1, 64);
    asm volatile("s_waitcnt vmcnt(6)" ::: "memory");
    __builtin_amdgcn_sched_barrier(0);
    __builtin_amdgcn_s_barrier();
    __builtin_amdgcn_sched_barrier(0);

    int cur = 0, nxt = 1, nn = 2;
    for (int t = 0; t < NKT; ++t) {
        if (t + 2 < NKT) STAGE(nn, (t + 2) * 64);

        const unsigned short* as = &As[0][0] + cur * (BM * 64);
        const unsigned short* bs = &Bs[0][0] + cur * (BN * 64);
#pragma unroll
        for (int ks = 0; ks < 2; ++ks) {
            const int kb  = (ks * 32 + lk) >> 3;
            const int kel = (kb ^ sb) * 8;
            bf16x8 af[4], bf[4];
#pragma unroll
            for (int i = 0; i < 4; ++i)
                af[i] = *(const bf16x8*)&as[(wr * 64 + i * 16 + lr) * 64 + kel];
#pragma unroll
            for (int j = 0; j < 4; ++j)
                bf[j] = *(const bf16x8*)&bs[(wc * 64 + j * 16 + lr) * 64 + kel];
#pragma unroll
            for (int i = 0; i < 4; ++i)
#pragma unroll
                for (int j = 0; j < 4; ++j)
                    acc[i][j] = __builtin_amdgcn_mfma_f32_16x16x32_bf16(
                        af[i], bf[j], acc[i][j], 0, 0, 0);
        }

        if (t + 2 < NKT) {
            asm volatile("s_waitcnt vmcnt(6)" ::: "memory");   // tile t+1 done
            __builtin_amdgcn_sched_barrier(0);
            __builtin_amdgcn_s_barrier();
            __builtin_amdgcn_sched_barrier(0);
        } else if (t + 1 < NKT) {
            asm volatile("s_waitcnt vmcnt(0)" ::: "memory");   // last tile
            __builtin_amdgcn_sched_barrier(0);
            __builtin_amdgcn_s_barrier();
            __builtin_amdgcn_sched_barrier(0);
        }
        const int tmp = cur; cur = nxt; nxt = nn; nn = tmp;
    }

    float bn[4];
#pragma unroll
    for (int j = 0; j < 4; ++j)
        bn[j] = bias[nt * BN + wc * 64 + j * 16 + lr];

#pragma unroll
    for (int i = 0; i < 4; ++i) {
        const int mbase = mt * BM + wr * 64 + i * 16 + (lane >> 4) * 4;
#pragma unroll
        for (int r = 0; r < 4; ++r) {
            const int m = mbase + r;
            if (m < Mrows) {
#pragma unroll
                for (int j = 0; j < 4; ++j) {
                    const int n = nt * BN + wc * 64 + j * 16 + lr;
                    out[(size_t)m * ODIM + n] = acc[i][j][r] + bn[j];
                }
            }
        }
    }
#undef STAGE
}

extern "C" void kernel_launch(void* const* d_in, const int* in_sizes, int n_in,
                              void* d_out, int out_size, void* d_ws, size_t ws_size,
                              hipStream_t stream) {
    const float* inp  = (const float*)d_in[0];
    const float* W    = (const float*)d_in[1];
    const float* bias = (const float*)d_in[2];
    float* out = (float*)d_out;

    const size_t wbBytes = (size_t)ODIM * KPAD * sizeof(unsigned short);
    const size_t sigPB   = (size_t)TSTEPS * KPAD * sizeof(unsigned short); // 2.42 MB
    const size_t ckptPB  = (size_t)15 * NSIG * sizeof(float);              // 0.28 MB
    const size_t perB    = sigPB + ckptPB;

    int nbMax = (int)((ws_size - wbBytes) / perB);
    if (nbMax > BATCH) nbMax = BATCH;
    if (nbMax < 1) nbMax = 1;

    unsigned short* sig  = (unsigned short*)d_ws;
    float*          ckpt = (float*)((char*)d_ws + (size_t)nbMax * sigPB);
    unsigned short* Wb   = (unsigned short*)((char*)d_ws + (ws_size - wbBytes));

    wcvt_kernel<<<(ODIM * KPAD + 255) / 256, 256, 0, stream>>>(W, Wb);

    for (int b0 = 0; b0 < BATCH; b0 += nbMax) {
        const int nb = (b0 + nbMax <= BATCH) ? nbMax : (BATCH - b0);
        const int Mrows = nb * TSTEPS;
        const float* ipb = inp + (size_t)b0 * LSEQ * CIN;
        sig_ckpt_kernel<<<nb, 512, 0, stream>>>(ipb, ckpt);
        sig_write_kernel<<<dim3(NCHUNK, nb), 512, 0, stream>>>(ipb, ckpt, sig);
        gemm_kernel<<<dim3(ODIM / BN, (Mrows + BM - 1) / BM), 512, 0, stream>>>(
            sig, Wb, bias, out + (size_t)b0 * TSTEPS * ODIM, Mrows);
    }
}

// Round 8
// 153.116 us; speedup vs baseline: 1.1546x; 1.1546x over previous
//
#include <hip/hip_runtime.h>
#include <hip/hip_bf16.h>

// Problem constants (QREncoder: path signature depth 4 + linear head)
#define BATCH 64
#define LSEQ 256
#define CIN 7
#define CC 8           // channels incl. time
#define NSIG 4680      // 8 + 64 + 512 + 4096
#define KPAD 4736      // NSIG padded to multiple of 64
#define TSTEPS 255     // LSEQ - 1
#define ODIM 512
#define NCHUNK 16      // time chunks for sig write parallelism
#define CH 16          // steps per chunk (last chunk: 15)
#define NKT 74         // KPAD / 64 K-steps
#define BM 256
#define BN 128

typedef __attribute__((ext_vector_type(8))) unsigned short ushort8;
typedef __attribute__((ext_vector_type(8))) __bf16 bf16x8;
typedef __attribute__((ext_vector_type(4))) float f32x4;

__device__ __forceinline__ unsigned short f2bf(float x) {
    __hip_bfloat16 h = __float2bfloat16(x);   // RNE
    return *(unsigned short*)&h;
}

#define GLDS16(gp, lp)                                                      \
    __builtin_amdgcn_global_load_lds(                                       \
        (const __attribute__((address_space(1))) void*)(gp),                \
        (__attribute__((address_space(3))) void*)(lp), 16, 0, 0)

// ---------------------------------------------------------------------------
// Scan pass A: one block per batch, sequential 255-step state-only scan,
// dumping full state (4680 f32) at t = 16,32,...,240 (15 checkpoints).
// ---------------------------------------------------------------------------
__global__ __launch_bounds__(512) void sig_ckpt_kernel(const float* __restrict__ inp,
                                                       float* __restrict__ ckpt) {
    __shared__ float sDx[TSTEPS * CC];

    const int b   = blockIdx.x;
    const int tid = threadIdx.x;

    const float* ip = inp + (size_t)b * LSEQ * CIN;
    for (int i = tid; i < TSTEPS * CC; i += 512) {
        int t = i >> 3, c = i & 7;
        sDx[i] = (c == 0) ? (1.0f / 255.0f)
                          : ip[(t + 1) * CIN + (c - 1)] - ip[t * CIN + (c - 1)];
    }
    __syncthreads();

    const int i1 = tid >> 6;
    const int i2 = (tid >> 3) & 7;
    const int i3 = tid & 7;

    float a1own = 0.0f, a2own = 0.0f, a3 = 0.0f;
    float a4[8];
#pragma unroll
    for (int e = 0; e < 8; ++e) a4[e] = 0.0f;

    for (int t = 0; t < 240; ++t) {
        const float* v = &sDx[t * CC];
        const float4 vlo = *(const float4*)&v[0];
        const float4 vhi = *(const float4*)&v[4];
        const float va = v[i1], vb = v[i2], vc = v[i3];
        const float e3s = va * vb * vc * (1.0f / 6.0f);
        const float T4 = e3s * 0.25f + a1own * vb * vc * (1.0f / 6.0f)
                       + a2own * vc * 0.5f + a3;
        a4[0] += vlo.x * T4; a4[1] += vlo.y * T4;
        a4[2] += vlo.z * T4; a4[3] += vlo.w * T4;
        a4[4] += vhi.x * T4; a4[5] += vhi.y * T4;
        a4[6] += vhi.z * T4; a4[7] += vhi.w * T4;
        a3 += e3s + (a1own * vb * 0.5f + a2own) * vc;
        a2own += vb * (0.5f * va + a1own);
        a1own += va;

        if (((t + 1) & 15) == 0) {            // t+1 in {16,...,240}
            const int c = ((t + 1) >> 4) - 1; // 0..14
            float* cp = ckpt + ((size_t)b * 15 + c) * NSIG;
            if ((tid & 63) == 0) cp[i1] = a1own;
            if ((tid & 7) == 0) cp[8 + (tid >> 3)] = a2own;
            cp[72 + tid] = a3;
            float4 q0 = {a4[0], a4[1], a4[2], a4[3]};
            float4 q1 = {a4[4], a4[5], a4[6], a4[7]};
            *(float4*)&cp[584 + tid * 8]     = q0;
            *(float4*)&cp[584 + tid * 8 + 4] = q1;
        }
    }
}

// ---------------------------------------------------------------------------
// Scan pass B: grid (NCHUNK, nb). Block (chunk,b) loads the chunk's start
// state from ckpt (chunk 0: zeros), runs <=16 steps, writes sig rows (bf16).
// ---------------------------------------------------------------------------
__global__ __launch_bounds__(512) void sig_write_kernel(const float* __restrict__ inp,
                                                        const float* __restrict__ ckpt,
                                                        unsigned short* __restrict__ sig) {
    __shared__ float sDx[CH * CC];

    const int chunk = blockIdx.x;
    const int b     = blockIdx.y;
    const int tid   = threadIdx.x;
    const int t0    = chunk * CH;
    const int t1    = (chunk == NCHUNK - 1) ? TSTEPS : t0 + CH;

    const float* ip = inp + (size_t)b * LSEQ * CIN;
    for (int i = tid; i < (t1 - t0) * CC; i += 512) {
        int t = t0 + (i >> 3), c = i & 7;
        sDx[i] = (c == 0) ? (1.0f / 255.0f)
                          : ip[(t + 1) * CIN + (c - 1)] - ip[t * CIN + (c - 1)];
    }
    __syncthreads();

    const int i1 = tid >> 6;
    const int i2 = (tid >> 3) & 7;
    const int i3 = tid & 7;

    float a1own, a2own, a3;
    float a4[8];
    if (chunk == 0) {
        a1own = a2own = a3 = 0.0f;
#pragma unroll
        for (int e = 0; e < 8; ++e) a4[e] = 0.0f;
    } else {
        const float* cp = ckpt + ((size_t)b * 15 + (chunk - 1)) * NSIG;
        a1own = cp[i1];
        a2own = cp[8 + (tid >> 3)];
        a3    = cp[72 + tid];
        float4 q0 = *(const float4*)&cp[584 + tid * 8];
        float4 q1 = *(const float4*)&cp[584 + tid * 8 + 4];
        a4[0] = q0.x; a4[1] = q0.y; a4[2] = q0.z; a4[3] = q0.w;
        a4[4] = q1.x; a4[5] = q1.y; a4[6] = q1.z; a4[7] = q1.w;
    }

    for (int t = t0; t < t1; ++t) {
        const float* v = &sDx[(t - t0) * CC];
        const float4 vlo = *(const float4*)&v[0];
        const float4 vhi = *(const float4*)&v[4];
        const float va = v[i1], vb = v[i2], vc = v[i3];
        const float e3s = va * vb * vc * (1.0f / 6.0f);
        const float T4 = e3s * 0.25f + a1own * vb * vc * (1.0f / 6.0f)
                       + a2own * vc * 0.5f + a3;
        a4[0] += vlo.x * T4; a4[1] += vlo.y * T4;
        a4[2] += vlo.z * T4; a4[3] += vlo.w * T4;
        a4[4] += vhi.x * T4; a4[5] += vhi.y * T4;
        a4[6] += vhi.z * T4; a4[7] += vhi.w * T4;
        a3 += e3s + (a1own * vb * 0.5f + a2own) * vc;
        a2own += vb * (0.5f * va + a1own);
        a1own += va;

        unsigned short* row = sig + ((size_t)b * TSTEPS + t) * KPAD;
        ushort8 pack;
#pragma unroll
        for (int e = 0; e < 8; ++e) pack[e] = f2bf(a4[e]);
        *(ushort8*)(row + 584 + tid * 8) = pack;                // level 4
        row[72 + tid] = f2bf(a3);                               // level 3
        if ((tid & 63) == 0) row[i1] = f2bf(a1own);             // level 1
        if ((tid & 7) == 0) row[8 + (tid >> 3)] = f2bf(a2own);  // level 2
        if (tid >= 448 && tid < 504) row[4232 + tid] = 0;       // pad
    }
}

// ---------------------------------------------------------------------------
// W fp32 [512][4680] -> bf16 [512][KPAD] (pad zeroed)
// ---------------------------------------------------------------------------
__global__ __launch_bounds__(256) void wcvt_kernel(const float* __restrict__ W,
                                                   unsigned short* __restrict__ Wb) {
    int idx = blockIdx.x * 256 + threadIdx.x;
    if (idx >= ODIM * KPAD) return;
    int n = idx / KPAD, k = idx - n * KPAD;
    Wb[idx] = (k < NSIG) ? f2bf(W[(size_t)n * NSIG + k]) : (unsigned short)0;
}

// ---------------------------------------------------------------------------
// MFMA GEMM, m201-style phase schedule.
// BM=256 x BN=128, BK=64, 8 waves (4Mx2N, each 64x64), 3 LDS buffers
// (144 KB, 1 block/CU, grid=256). Iteration t computes K-tile t (buf cur)
// in 2 phases (one per ks-slice, 16 MFMA each) while staging K-tile t+2
// (buf nn, 3 gloads per phase). Phase: {8 ds_read_b128 | 3 gload} ->
// s_barrier -> lgkmcnt(0) -> sched_barrier -> setprio(1) 16 MFMA setprio(0)
// -> s_barrier. End of iter: vmcnt(6) (tile t+1 complete; t+2's 6 loads
// REMAIN IN FLIGHT across the barrier - never drain to 0 in the loop).
// T2 XOR-swizzle (conflicts==0), XCD-grouped block swizzle.
// ---------------------------------------------------------------------------
__global__ __launch_bounds__(512) void gemm_kernel(const unsigned short* __restrict__ A,
                                                   const unsigned short* __restrict__ Wb,
                                                   const float* __restrict__ bias,
                                                   float* __restrict__ out,
                                                   int Mrows) {
    __shared__ unsigned short As[3][BM * 64];   // 3 x 32 KB
    __shared__ unsigned short Bs[3][BN * 64];   // 3 x 16 KB

    const int tid = threadIdx.x;
    int nt, mt;
    if (gridDim.y == 64) {                     // full dispatch (256 blocks)
        const int li = blockIdx.y * 4 + blockIdx.x;
        const int x  = li & 7;                 // XCD (round-robin assumption)
        const int j  = li >> 3;                // 0..31 within XCD
        mt = x * 8 + (j >> 2);                 // 8 m-panels per XCD
        nt = j & 3;
    } else {
        nt = blockIdx.x; mt = blockIdx.y;
    }
    const int lane = tid & 63;
    const int wv   = tid >> 6;                 // 0..7
    const int wr   = wv >> 1;                  // 0..3 (M)
    const int wc   = wv & 1;                   // 0..1 (N)
    const int lr   = lane & 15;
    const int lq   = lane >> 4;                // 0..3
    const int sb   = lr & 7;                   // read-side swizzle key

    const f32x4 z4 = {0.0f, 0.0f, 0.0f, 0.0f};
    f32x4 acc[4][4];
#pragma unroll
    for (int i = 0; i < 4; ++i)
#pragma unroll
        for (int j = 0; j < 4; ++j) acc[i][j] = z4;

    const int srow = tid >> 3;                          // 0..63
    const int gcb  = (tid & 7) ^ (srow & 7);            // pre-swizzled src blk
    const int scol = gcb * 8;

    // per-lane global source pointers (A rows clamped for M-tail)
    const unsigned short* aptr[4];
    const unsigned short* bptr[2];
#pragma unroll
    for (int i = 0; i < 4; ++i) {
        int gr = mt * BM + i * 64 + srow;
        if (gr >= Mrows) gr = 0;
        aptr[i] = A + (size_t)gr * KPAD + scol;
    }
#pragma unroll
    for (int i = 0; i < 2; ++i)
        bptr[i] = Wb + (size_t)(nt * BN + i * 64 + srow) * KPAD + scol;

    // swizzled element columns for the two ks slices
    const int kel0 = ((lq)     ^ sb) * 8;               // ks=0: kb = lq
    const int kel1 = ((4 + lq) ^ sb) * 8;               // ks=1: kb = 4+lq

#define STAGE_ALL(buf, koff)                                                \
    do {                                                                    \
        _Pragma("unroll")                                                   \
        for (int i_ = 0; i_ < 4; ++i_)                                      \
            GLDS16(aptr[i_] + (koff),                                       \
                   ((char*)As[buf]) + i_ * 8192 + tid * 16);                \
        _Pragma("unroll")                                                   \
        for (int i_ = 0; i_ < 2; ++i_)                                      \
            GLDS16(bptr[i_] + (koff),                                       \
                   ((char*)Bs[buf]) + i_ * 8192 + tid * 16);                \
    } while (0)

    // prologue: tiles 0 and 1 in flight; wait tile 0 (6 of tile 1 remain)
    STAGE_ALL(0, 0);
    STAGE_ALL(1, 64);
    asm volatile("s_waitcnt vmcnt(6)" ::: "memory");
    __builtin_amdgcn_sched_barrier(0);
    __builtin_amdgcn_s_barrier();
    __builtin_amdgcn_sched_barrier(0);

    int cur = 0, nxt = 1, nn = 2;
    for (int t = 0; t < NKT; ++t) {
        const unsigned short* as = &As[0][0] + cur * (BM * 64);
        const unsigned short* bs = &Bs[0][0] + cur * (BN * 64);
        const bool st = (t + 2 < NKT);
        const int koff = (t + 2) * 64;
        char* dstA = (char*)As[0] + nn * (BM * 64 * 2);
        char* dstB = (char*)Bs[0] + nn * (BN * 64 * 2);

        // ================= phase 0 (ks = 0) =================
        {
            bf16x8 af[4], bf[4];
#pragma unroll
            for (int i = 0; i < 4; ++i)
                af[i] = *(const bf16x8*)&as[(wr * 64 + i * 16 + lr) * 64 + kel0];
#pragma unroll
            for (int j = 0; j < 4; ++j)
                bf[j] = *(const bf16x8*)&bs[(wc * 64 + j * 16 + lr) * 64 + kel0];
            if (st) {
                GLDS16(aptr[0] + koff, dstA + 0 * 8192 + tid * 16);
                GLDS16(aptr[1] + koff, dstA + 1 * 8192 + tid * 16);
                GLDS16(aptr[2] + koff, dstA + 2 * 8192 + tid * 16);
            }
            __builtin_amdgcn_sched_barrier(0);
            __builtin_amdgcn_s_barrier();
            asm volatile("s_waitcnt lgkmcnt(0)" ::: "memory");
            __builtin_amdgcn_sched_barrier(0);
            __builtin_amdgcn_s_setprio(1);
#pragma unroll
            for (int i = 0; i < 4; ++i)
#pragma unroll
                for (int j = 0; j < 4; ++j)
                    acc[i][j] = __builtin_amdgcn_mfma_f32_16x16x32_bf16(
                        af[i], bf[j], acc[i][j], 0, 0, 0);
            __builtin_amdgcn_s_setprio(0);
            __builtin_amdgcn_sched_barrier(0);
            __builtin_amdgcn_s_barrier();
        }

        // ================= phase 1 (ks = 1) =================
        {
            bf16x8 af[4], bf[4];
#pragma unroll
            for (int i = 0; i < 4; ++i)
                af[i] = *(const bf16x8*)&as[(wr * 64 + i * 16 + lr) * 64 + kel1];
#pragma unroll
            for (int j = 0; j < 4; ++j)
                bf[j] = *(const bf16x8*)&bs[(wc * 64 + j * 16 + lr) * 64 + kel1];
            if (st) {
                GLDS16(aptr[3] + koff, dstA + 3 * 8192 + tid * 16);
                GLDS16(bptr[0] + koff, dstB + 0 * 8192 + tid * 16);
                GLDS16(bptr[1] + koff, dstB + 1 * 8192 + tid * 16);
            }
            __builtin_amdgcn_sched_barrier(0);
            __builtin_amdgcn_s_barrier();
            asm volatile("s_waitcnt lgkmcnt(0)" ::: "memory");
            __builtin_amdgcn_sched_barrier(0);
            __builtin_amdgcn_s_setprio(1);
#pragma unroll
            for (int i = 0; i < 4; ++i)
#pragma unroll
                for (int j = 0; j < 4; ++j)
                    acc[i][j] = __builtin_amdgcn_mfma_f32_16x16x32_bf16(
                        af[i], bf[j], acc[i][j], 0, 0, 0);
            __builtin_amdgcn_s_setprio(0);
            __builtin_amdgcn_sched_barrier(0);
            // counted wait: tile t+1 complete, tile t+2 stays in flight
            if (st) {
                asm volatile("s_waitcnt vmcnt(6)" ::: "memory");
            } else if (t + 1 < NKT) {
                asm volatile("s_waitcnt vmcnt(0)" ::: "memory");
            }
            __builtin_amdgcn_sched_barrier(0);
            __builtin_amdgcn_s_barrier();
        }

        const int tmp = cur; cur = nxt; nxt = nn; nn = tmp;
    }

    float bn[4];
#pragma unroll
    for (int j = 0; j < 4; ++j)
        bn[j] = bias[nt * BN + wc * 64 + j * 16 + lr];

#pragma unroll
    for (int i = 0; i < 4; ++i) {
        const int mbase = mt * BM + wr * 64 + i * 16 + lq * 4;
#pragma unroll
        for (int r = 0; r < 4; ++r) {
            const int m = mbase + r;
            if (m < Mrows) {
#pragma unroll
                for (int j = 0; j < 4; ++j) {
                    const int n = nt * BN + wc * 64 + j * 16 + lr;
                    out[(size_t)m * ODIM + n] = acc[i][j][r] + bn[j];
                }
            }
        }
    }
#undef STAGE_ALL
}

extern "C" void kernel_launch(void* const* d_in, const int* in_sizes, int n_in,
                              void* d_out, int out_size, void* d_ws, size_t ws_size,
                              hipStream_t stream) {
    const float* inp  = (const float*)d_in[0];
    const float* W    = (const float*)d_in[1];
    const float* bias = (const float*)d_in[2];
    float* out = (float*)d_out;

    const size_t wbBytes = (size_t)ODIM * KPAD * sizeof(unsigned short);
    const size_t sigPB   = (size_t)TSTEPS * KPAD * sizeof(unsigned short); // 2.42 MB
    const size_t ckptPB  = (size_t)15 * NSIG * sizeof(float);              // 0.28 MB
    const size_t perB    = sigPB + ckptPB;

    int nbMax = (int)((ws_size - wbBytes) / perB);
    if (nbMax > BATCH) nbMax = BATCH;
    if (nbMax < 1) nbMax = 1;

    unsigned short* sig  = (unsigned short*)d_ws;
    float*          ckpt = (float*)((char*)d_ws + (size_t)nbMax * sigPB);
    unsigned short* Wb   = (unsigned short*)((char*)d_ws + (ws_size - wbBytes));

    wcvt_kernel<<<(ODIM * KPAD + 255) / 256, 256, 0, stream>>>(W, Wb);

    for (int b0 = 0; b0 < BATCH; b0 += nbMax) {
        const int nb = (b0 + nbMax <= BATCH) ? nbMax : (BATCH - b0);
        const int Mrows = nb * TSTEPS;
        const float* ipb = inp + (size_t)b0 * LSEQ * CIN;
        sig_ckpt_kernel<<<nb, 512, 0, stream>>>(ipb, ckpt);
        sig_write_kernel<<<dim3(NCHUNK, nb), 512, 0, stream>>>(ipb, ckpt, sig);
        gemm_kernel<<<dim3(ODIM / BN, (Mrows + BM - 1) / BM), 512, 0, stream>>>(
            sig, Wb, bias, out + (size_t)b0 * TSTEPS * ODIM, Mrows);
    }
}

// Round 9
// 148.912 us; speedup vs baseline: 1.1872x; 1.0282x over previous
//
#include <hip/hip_runtime.h>
#include <hip/hip_bf16.h>

// Problem constants (QREncoder: path signature depth 4 + linear head)
#define BATCH 64
#define LSEQ 256
#define CIN 7
#define CC 8           // channels incl. time
#define NSIG 4680      // 8 + 64 + 512 + 4096
#define KPAD 4736      // NSIG padded to multiple of 64
#define TSTEPS 255     // LSEQ - 1
#define ODIM 512
#define NCHUNK 16      // time chunks for sig write parallelism
#define CH 16          // steps per chunk (last chunk: 15)
#define NKT 74         // KPAD / 64 K-steps
#define BM 256
#define BN 128

typedef __attribute__((ext_vector_type(8))) unsigned short ushort8;
typedef __attribute__((ext_vector_type(8))) __bf16 bf16x8;
typedef __attribute__((ext_vector_type(4))) float f32x4;

__device__ __forceinline__ unsigned short f2bf(float x) {
    __hip_bfloat16 h = __float2bfloat16(x);   // RNE
    return *(unsigned short*)&h;
}

#define GLDS16(gp, lp)                                                      \
    __builtin_amdgcn_global_load_lds(                                       \
        (const __attribute__((address_space(1))) void*)(gp),                \
        (__attribute__((address_space(3))) void*)(lp), 16, 0, 0)

// ---------------------------------------------------------------------------
// Scan pass A: one block per batch, sequential 255-step state-only scan,
// dumping full state (4680 f32) at t = 16,32,...,240 (15 checkpoints).
// ---------------------------------------------------------------------------
__global__ __launch_bounds__(512) void sig_ckpt_kernel(const float* __restrict__ inp,
                                                       float* __restrict__ ckpt) {
    __shared__ float sDx[TSTEPS * CC];

    const int b   = blockIdx.x;
    const int tid = threadIdx.x;

    const float* ip = inp + (size_t)b * LSEQ * CIN;
    for (int i = tid; i < TSTEPS * CC; i += 512) {
        int t = i >> 3, c = i & 7;
        sDx[i] = (c == 0) ? (1.0f / 255.0f)
                          : ip[(t + 1) * CIN + (c - 1)] - ip[t * CIN + (c - 1)];
    }
    __syncthreads();

    const int i1 = tid >> 6;
    const int i2 = (tid >> 3) & 7;
    const int i3 = tid & 7;

    float a1own = 0.0f, a2own = 0.0f, a3 = 0.0f;
    float a4[8];
#pragma unroll
    for (int e = 0; e < 8; ++e) a4[e] = 0.0f;

    for (int t = 0; t < 240; ++t) {
        const float* v = &sDx[t * CC];
        const float4 vlo = *(const float4*)&v[0];
        const float4 vhi = *(const float4*)&v[4];
        const float va = v[i1], vb = v[i2], vc = v[i3];
        const float e3s = va * vb * vc * (1.0f / 6.0f);
        const float T4 = e3s * 0.25f + a1own * vb * vc * (1.0f / 6.0f)
                       + a2own * vc * 0.5f + a3;
        a4[0] += vlo.x * T4; a4[1] += vlo.y * T4;
        a4[2] += vlo.z * T4; a4[3] += vlo.w * T4;
        a4[4] += vhi.x * T4; a4[5] += vhi.y * T4;
        a4[6] += vhi.z * T4; a4[7] += vhi.w * T4;
        a3 += e3s + (a1own * vb * 0.5f + a2own) * vc;
        a2own += vb * (0.5f * va + a1own);
        a1own += va;

        if (((t + 1) & 15) == 0) {            // t+1 in {16,...,240}
            const int c = ((t + 1) >> 4) - 1; // 0..14
            float* cp = ckpt + ((size_t)b * 15 + c) * NSIG;
            if ((tid & 63) == 0) cp[i1] = a1own;
            if ((tid & 7) == 0) cp[8 + (tid >> 3)] = a2own;
            cp[72 + tid] = a3;
            float4 q0 = {a4[0], a4[1], a4[2], a4[3]};
            float4 q1 = {a4[4], a4[5], a4[6], a4[7]};
            *(float4*)&cp[584 + tid * 8]     = q0;
            *(float4*)&cp[584 + tid * 8 + 4] = q1;
        }
    }
}

// ---------------------------------------------------------------------------
// Scan pass B: grid (NCHUNK, nb). Block (chunk,b) loads the chunk's start
// state from ckpt (chunk 0: zeros), runs <=16 steps, writes sig rows (bf16).
// ---------------------------------------------------------------------------
__global__ __launch_bounds__(512) void sig_write_kernel(const float* __restrict__ inp,
                                                        const float* __restrict__ ckpt,
                                                        unsigned short* __restrict__ sig) {
    __shared__ float sDx[CH * CC];

    const int chunk = blockIdx.x;
    const int b     = blockIdx.y;
    const int tid   = threadIdx.x;
    const int t0    = chunk * CH;
    const int t1    = (chunk == NCHUNK - 1) ? TSTEPS : t0 + CH;

    const float* ip = inp + (size_t)b * LSEQ * CIN;
    for (int i = tid; i < (t1 - t0) * CC; i += 512) {
        int t = t0 + (i >> 3), c = i & 7;
        sDx[i] = (c == 0) ? (1.0f / 255.0f)
                          : ip[(t + 1) * CIN + (c - 1)] - ip[t * CIN + (c - 1)];
    }
    __syncthreads();

    const int i1 = tid >> 6;
    const int i2 = (tid >> 3) & 7;
    const int i3 = tid & 7;

    float a1own, a2own, a3;
    float a4[8];
    if (chunk == 0) {
        a1own = a2own = a3 = 0.0f;
#pragma unroll
        for (int e = 0; e < 8; ++e) a4[e] = 0.0f;
    } else {
        const float* cp = ckpt + ((size_t)b * 15 + (chunk - 1)) * NSIG;
        a1own = cp[i1];
        a2own = cp[8 + (tid >> 3)];
        a3    = cp[72 + tid];
        float4 q0 = *(const float4*)&cp[584 + tid * 8];
        float4 q1 = *(const float4*)&cp[584 + tid * 8 + 4];
        a4[0] = q0.x; a4[1] = q0.y; a4[2] = q0.z; a4[3] = q0.w;
        a4[4] = q1.x; a4[5] = q1.y; a4[6] = q1.z; a4[7] = q1.w;
    }

    for (int t = t0; t < t1; ++t) {
        const float* v = &sDx[(t - t0) * CC];
        const float4 vlo = *(const float4*)&v[0];
        const float4 vhi = *(const float4*)&v[4];
        const float va = v[i1], vb = v[i2], vc = v[i3];
        const float e3s = va * vb * vc * (1.0f / 6.0f);
        const float T4 = e3s * 0.25f + a1own * vb * vc * (1.0f / 6.0f)
                       + a2own * vc * 0.5f + a3;
        a4[0] += vlo.x * T4; a4[1] += vlo.y * T4;
        a4[2] += vlo.z * T4; a4[3] += vlo.w * T4;
        a4[4] += vhi.x * T4; a4[5] += vhi.y * T4;
        a4[6] += vhi.z * T4; a4[7] += vhi.w * T4;
        a3 += e3s + (a1own * vb * 0.5f + a2own) * vc;
        a2own += vb * (0.5f * va + a1own);
        a1own += va;

        unsigned short* row = sig + ((size_t)b * TSTEPS + t) * KPAD;
        ushort8 pack;
#pragma unroll
        for (int e = 0; e < 8; ++e) pack[e] = f2bf(a4[e]);
        *(ushort8*)(row + 584 + tid * 8) = pack;                // level 4
        row[72 + tid] = f2bf(a3);                               // level 3
        if ((tid & 63) == 0) row[i1] = f2bf(a1own);             // level 1
        if ((tid & 7) == 0) row[8 + (tid >> 3)] = f2bf(a2own);  // level 2
        if (tid >= 448 && tid < 504) row[4232 + tid] = 0;       // pad
    }
}

// ---------------------------------------------------------------------------
// W fp32 [512][4680] -> bf16 [512][KPAD] (pad zeroed)
// ---------------------------------------------------------------------------
__global__ __launch_bounds__(256) void wcvt_kernel(const float* __restrict__ W,
                                                   unsigned short* __restrict__ Wb) {
    int idx = blockIdx.x * 256 + threadIdx.x;
    if (idx >= ODIM * KPAD) return;
    int n = idx / KPAD, k = idx - n * KPAD;
    Wb[idx] = (k < NSIG) ? f2bf(W[(size_t)n * NSIG + k]) : (unsigned short)0;
}

// ---------------------------------------------------------------------------
// MFMA GEMM, software-pipelined phases (R9).
// BM=256 x BN=128, BK=64, 8 waves (4Mx2N, each 64x64), 3 LDS buffers
// (144 KB, 1 block/CU, grid=256).
// R8 post-mortem: the lockstep {reads; bar; MFMA; bar} per phase SERIALIZED
// the LDS pipe (768cy/phase) and the MFMA cluster (516cy/phase). R9: issue
// BOTH phases' 16 ds_reads (ph0->afP/bfP, ph1->afN/bfN) + the 6 gloads up
// front, lgkmcnt(8) -> MFMA ph0 (ph1 reads stream underneath) -> lgkmcnt(0)
// -> MFMA ph1. ONE barrier per K-tile, counted vmcnt(6) (tile t+2's loads
// stay in flight across it). sched_barrier(0) fences (rule #18).
// T2 XOR-swizzle (conflicts==0), XCD-grouped block swizzle.
// ---------------------------------------------------------------------------
__global__ __launch_bounds__(512) void gemm_kernel(const unsigned short* __restrict__ A,
                                                   const unsigned short* __restrict__ Wb,
                                                   const float* __restrict__ bias,
                                                   float* __restrict__ out,
                                                   int Mrows) {
    __shared__ unsigned short As[3][BM * 64];   // 3 x 32 KB
    __shared__ unsigned short Bs[3][BN * 64];   // 3 x 16 KB

    const int tid = threadIdx.x;
    int nt, mt;
    if (gridDim.y == 64) {                     // full dispatch (256 blocks)
        const int li = blockIdx.y * 4 + blockIdx.x;
        const int x  = li & 7;                 // XCD (round-robin assumption)
        const int j  = li >> 3;                // 0..31 within XCD
        mt = x * 8 + (j >> 2);                 // 8 m-panels per XCD
        nt = j & 3;
    } else {
        nt = blockIdx.x; mt = blockIdx.y;
    }
    const int lane = tid & 63;
    const int wv   = tid >> 6;                 // 0..7
    const int wr   = wv >> 1;                  // 0..3 (M)
    const int wc   = wv & 1;                   // 0..1 (N)
    const int lr   = lane & 15;
    const int lq   = lane >> 4;                // 0..3
    const int sb   = lr & 7;                   // read-side swizzle key

    const f32x4 z4 = {0.0f, 0.0f, 0.0f, 0.0f};
    f32x4 acc[4][4];
#pragma unroll
    for (int i = 0; i < 4; ++i)
#pragma unroll
        for (int j = 0; j < 4; ++j) acc[i][j] = z4;

    const int srow = tid >> 3;                          // 0..63
    const int gcb  = (tid & 7) ^ (srow & 7);            // pre-swizzled src blk
    const int scol = gcb * 8;

    // per-lane global source pointers (A rows clamped for M-tail)
    const unsigned short* aptr[4];
    const unsigned short* bptr[2];
#pragma unroll
    for (int i = 0; i < 4; ++i) {
        int gr = mt * BM + i * 64 + srow;
        if (gr >= Mrows) gr = 0;
        aptr[i] = A + (size_t)gr * KPAD + scol;
    }
#pragma unroll
    for (int i = 0; i < 2; ++i)
        bptr[i] = Wb + (size_t)(nt * BN + i * 64 + srow) * KPAD + scol;

    // swizzled element columns for the two ks slices
    const int kel0 = ((lq)     ^ sb) * 8;               // ks=0: kb = lq
    const int kel1 = ((4 + lq) ^ sb) * 8;               // ks=1: kb = 4+lq

    // per-wave LDS fragment base offsets (element units)
    const int aoff = (wr * 64 + lr) * 64;               // + i*16*64
    const int boff = (wc * 64 + lr) * 64;               // + j*16*64

#define STAGE_ALL(buf, koff)                                                \
    do {                                                                    \
        _Pragma("unroll")                                                   \
        for (int i_ = 0; i_ < 4; ++i_)                                      \
            GLDS16(aptr[i_] + (koff),                                       \
                   ((char*)As[buf]) + i_ * 8192 + tid * 16);                \
        _Pragma("unroll")                                                   \
        for (int i_ = 0; i_ < 2; ++i_)                                      \
            GLDS16(bptr[i_] + (koff),                                       \
                   ((char*)Bs[buf]) + i_ * 8192 + tid * 16);                \
    } while (0)

    // prologue: tiles 0 and 1 in flight; wait tile 0 (6 of tile 1 remain)
    STAGE_ALL(0, 0);
    STAGE_ALL(1, 64);
    asm volatile("s_waitcnt vmcnt(6)" ::: "memory");
    __builtin_amdgcn_sched_barrier(0);
    __builtin_amdgcn_s_barrier();
    __builtin_amdgcn_sched_barrier(0);

    int cur = 0, nxt = 1, nn = 2;
    for (int t = 0; t < NKT; ++t) {
        const unsigned short* as = &As[0][0] + cur * (BM * 64);
        const unsigned short* bs = &Bs[0][0] + cur * (BN * 64);
        const bool st = (t + 2 < NKT);
        const int koff = (t + 2) * 64;

        // ---- issue ph0 reads (8), then ph1 reads (8), then 6 gloads ----
        bf16x8 afP[4], bfP[4], afN[4], bfN[4];
#pragma unroll
        for (int i = 0; i < 4; ++i)
            afP[i] = *(const bf16x8*)&as[aoff + i * 1024 + kel0];
#pragma unroll
        for (int j = 0; j < 4; ++j)
            bfP[j] = *(const bf16x8*)&bs[boff + j * 1024 + kel0];
#pragma unroll
        for (int i = 0; i < 4; ++i)
            afN[i] = *(const bf16x8*)&as[aoff + i * 1024 + kel1];
#pragma unroll
        for (int j = 0; j < 4; ++j)
            bfN[j] = *(const bf16x8*)&bs[boff + j * 1024 + kel1];
        if (st) STAGE_ALL(nn, koff);

        // ---- ph0 MFMA while ph1's reads stream in the LDS pipe ----
        asm volatile("s_waitcnt lgkmcnt(8)" ::: "memory");
        __builtin_amdgcn_sched_barrier(0);
        __builtin_amdgcn_s_setprio(1);
#pragma unroll
        for (int i = 0; i < 4; ++i)
#pragma unroll
            for (int j = 0; j < 4; ++j)
                acc[i][j] = __builtin_amdgcn_mfma_f32_16x16x32_bf16(
                    afP[i], bfP[j], acc[i][j], 0, 0, 0);
        __builtin_amdgcn_s_setprio(0);
        __builtin_amdgcn_sched_barrier(0);

        // ---- ph1 MFMA ----
        asm volatile("s_waitcnt lgkmcnt(0)" ::: "memory");
        __builtin_amdgcn_sched_barrier(0);
        __builtin_amdgcn_s_setprio(1);
#pragma unroll
        for (int i = 0; i < 4; ++i)
#pragma unroll
            for (int j = 0; j < 4; ++j)
                acc[i][j] = __builtin_amdgcn_mfma_f32_16x16x32_bf16(
                    afN[i], bfN[j], acc[i][j], 0, 0, 0);
        __builtin_amdgcn_s_setprio(0);
        __builtin_amdgcn_sched_barrier(0);

        // ---- one barrier per tile; counted vmcnt keeps t+2 in flight ----
        if (st) {
            asm volatile("s_waitcnt vmcnt(6)" ::: "memory");
            __builtin_amdgcn_sched_barrier(0);
            __builtin_amdgcn_s_barrier();
            __builtin_amdgcn_sched_barrier(0);
        } else if (t + 1 < NKT) {
            asm volatile("s_waitcnt vmcnt(0)" ::: "memory");
            __builtin_amdgcn_sched_barrier(0);
            __builtin_amdgcn_s_barrier();
            __builtin_amdgcn_sched_barrier(0);
        }

        const int tmp = cur; cur = nxt; nxt = nn; nn = tmp;
    }

    float bn[4];
#pragma unroll
    for (int j = 0; j < 4; ++j)
        bn[j] = bias[nt * BN + wc * 64 + j * 16 + lr];

#pragma unroll
    for (int i = 0; i < 4; ++i) {
        const int mbase = mt * BM + wr * 64 + i * 16 + lq * 4;
#pragma unroll
        for (int r = 0; r < 4; ++r) {
            const int m = mbase + r;
            if (m < Mrows) {
#pragma unroll
                for (int j = 0; j < 4; ++j) {
                    const int n = nt * BN + wc * 64 + j * 16 + lr;
                    out[(size_t)m * ODIM + n] = acc[i][j][r] + bn[j];
                }
            }
        }
    }
#undef STAGE_ALL
}

extern "C" void kernel_launch(void* const* d_in, const int* in_sizes, int n_in,
                              void* d_out, int out_size, void* d_ws, size_t ws_size,
                              hipStream_t stream) {
    const float* inp  = (const float*)d_in[0];
    const float* W    = (const float*)d_in[1];
    const float* bias = (const float*)d_in[2];
    float* out = (float*)d_out;

    const size_t wbBytes = (size_t)ODIM * KPAD * sizeof(unsigned short);
    const size_t sigPB   = (size_t)TSTEPS * KPAD * sizeof(unsigned short); // 2.42 MB
    const size_t ckptPB  = (size_t)15 * NSIG * sizeof(float);              // 0.28 MB
    const size_t perB    = sigPB + ckptPB;

    int nbMax = (int)((ws_size - wbBytes) / perB);
    if (nbMax > BATCH) nbMax = BATCH;
    if (nbMax < 1) nbMax = 1;

    unsigned short* sig  = (unsigned short*)d_ws;
    float*          ckpt = (float*)((char*)d_ws + (size_t)nbMax * sigPB);
    unsigned short* Wb   = (unsigned short*)((char*)d_ws + (ws_size - wbBytes));

    wcvt_kernel<<<(ODIM * KPAD + 255) / 256, 256, 0, stream>>>(W, Wb);

    for (int b0 = 0; b0 < BATCH; b0 += nbMax) {
        const int nb = (b0 + nbMax <= BATCH) ? nbMax : (BATCH - b0);
        const int Mrows = nb * TSTEPS;
        const float* ipb = inp + (size_t)b0 * LSEQ * CIN;
        sig_ckpt_kernel<<<nb, 512, 0, stream>>>(ipb, ckpt);
        sig_write_kernel<<<dim3(NCHUNK, nb), 512, 0, stream>>>(ipb, ckpt, sig);
        gemm_kernel<<<dim3(ODIM / BN, (Mrows + BM - 1) / BM), 512, 0, stream>>>(
            sig, Wb, bias, out + (size_t)b0 * TSTEPS * ODIM, Mrows);
    }
}

// Round 10
// 148.470 us; speedup vs baseline: 1.1907x; 1.0030x over previous
//
#include <hip/hip_runtime.h>
#include <hip/hip_bf16.h>

// Problem constants (QREncoder: path signature depth 4 + linear head)
#define BATCH 64
#define LSEQ 256
#define CIN 7
#define CC 8           // channels incl. time
#define NSIG 4680      // 8 + 64 + 512 + 4096
#define KPAD 4736      // NSIG padded to multiple of 64
#define TSTEPS 255     // LSEQ - 1
#define ODIM 512
#define NCHUNK 16      // time chunks for sig write parallelism
#define CH 16          // steps per chunk (last chunk: 15)
#define NKT 74         // KPAD / 64 K-steps
#define BM 256
#define BN 128

typedef __attribute__((ext_vector_type(8))) unsigned short ushort8;
typedef __attribute__((ext_vector_type(8))) __bf16 bf16x8;
typedef __attribute__((ext_vector_type(4))) float f32x4;

__device__ __forceinline__ unsigned short f2bf(float x) {
    __hip_bfloat16 h = __float2bfloat16(x);   // RNE
    return *(unsigned short*)&h;
}

#define GLDS16(gp, lp)                                                      \
    __builtin_amdgcn_global_load_lds(                                       \
        (const __attribute__((address_space(1))) void*)(gp),                \
        (__attribute__((address_space(3))) void*)(lp), 16, 0, 0)

// ---------------------------------------------------------------------------
// Scan pass A: one block per batch, sequential 255-step state-only scan,
// dumping full state (4680 f32) at t = 16,32,...,240 (15 checkpoints).
// ---------------------------------------------------------------------------
__global__ __launch_bounds__(512) void sig_ckpt_kernel(const float* __restrict__ inp,
                                                       float* __restrict__ ckpt) {
    __shared__ float sDx[TSTEPS * CC];

    const int b   = blockIdx.x;
    const int tid = threadIdx.x;

    const float* ip = inp + (size_t)b * LSEQ * CIN;
    for (int i = tid; i < TSTEPS * CC; i += 512) {
        int t = i >> 3, c = i & 7;
        sDx[i] = (c == 0) ? (1.0f / 255.0f)
                          : ip[(t + 1) * CIN + (c - 1)] - ip[t * CIN + (c - 1)];
    }
    __syncthreads();

    const int i1 = tid >> 6;
    const int i2 = (tid >> 3) & 7;
    const int i3 = tid & 7;

    float a1own = 0.0f, a2own = 0.0f, a3 = 0.0f;
    float a4[8];
#pragma unroll
    for (int e = 0; e < 8; ++e) a4[e] = 0.0f;

    for (int t = 0; t < 240; ++t) {
        const float* v = &sDx[t * CC];
        const float4 vlo = *(const float4*)&v[0];
        const float4 vhi = *(const float4*)&v[4];
        const float va = v[i1], vb = v[i2], vc = v[i3];
        const float e3s = va * vb * vc * (1.0f / 6.0f);
        const float T4 = e3s * 0.25f + a1own * vb * vc * (1.0f / 6.0f)
                       + a2own * vc * 0.5f + a3;
        a4[0] += vlo.x * T4; a4[1] += vlo.y * T4;
        a4[2] += vlo.z * T4; a4[3] += vlo.w * T4;
        a4[4] += vhi.x * T4; a4[5] += vhi.y * T4;
        a4[6] += vhi.z * T4; a4[7] += vhi.w * T4;
        a3 += e3s + (a1own * vb * 0.5f + a2own) * vc;
        a2own += vb * (0.5f * va + a1own);
        a1own += va;

        if (((t + 1) & 15) == 0) {            // t+1 in {16,...,240}
            const int c = ((t + 1) >> 4) - 1; // 0..14
            float* cp = ckpt + ((size_t)b * 15 + c) * NSIG;
            if ((tid & 63) == 0) cp[i1] = a1own;
            if ((tid & 7) == 0) cp[8 + (tid >> 3)] = a2own;
            cp[72 + tid] = a3;
            float4 q0 = {a4[0], a4[1], a4[2], a4[3]};
            float4 q1 = {a4[4], a4[5], a4[6], a4[7]};
            *(float4*)&cp[584 + tid * 8]     = q0;
            *(float4*)&cp[584 + tid * 8 + 4] = q1;
        }
    }
}

// ---------------------------------------------------------------------------
// Scan pass B: grid (NCHUNK, nb). Block (chunk,b) loads the chunk's start
// state from ckpt (chunk 0: zeros), runs <=16 steps, writes sig rows (bf16).
// ---------------------------------------------------------------------------
__global__ __launch_bounds__(512) void sig_write_kernel(const float* __restrict__ inp,
                                                        const float* __restrict__ ckpt,
                                                        unsigned short* __restrict__ sig) {
    __shared__ float sDx[CH * CC];

    const int chunk = blockIdx.x;
    const int b     = blockIdx.y;
    const int tid   = threadIdx.x;
    const int t0    = chunk * CH;
    const int t1    = (chunk == NCHUNK - 1) ? TSTEPS : t0 + CH;

    const float* ip = inp + (size_t)b * LSEQ * CIN;
    for (int i = tid; i < (t1 - t0) * CC; i += 512) {
        int t = t0 + (i >> 3), c = i & 7;
        sDx[i] = (c == 0) ? (1.0f / 255.0f)
                          : ip[(t + 1) * CIN + (c - 1)] - ip[t * CIN + (c - 1)];
    }
    __syncthreads();

    const int i1 = tid >> 6;
    const int i2 = (tid >> 3) & 7;
    const int i3 = tid & 7;

    float a1own, a2own, a3;
    float a4[8];
    if (chunk == 0) {
        a1own = a2own = a3 = 0.0f;
#pragma unroll
        for (int e = 0; e < 8; ++e) a4[e] = 0.0f;
    } else {
        const float* cp = ckpt + ((size_t)b * 15 + (chunk - 1)) * NSIG;
        a1own = cp[i1];
        a2own = cp[8 + (tid >> 3)];
        a3    = cp[72 + tid];
        float4 q0 = *(const float4*)&cp[584 + tid * 8];
        float4 q1 = *(const float4*)&cp[584 + tid * 8 + 4];
        a4[0] = q0.x; a4[1] = q0.y; a4[2] = q0.z; a4[3] = q0.w;
        a4[4] = q1.x; a4[5] = q1.y; a4[6] = q1.z; a4[7] = q1.w;
    }

    for (int t = t0; t < t1; ++t) {
        const float* v = &sDx[(t - t0) * CC];
        const float4 vlo = *(const float4*)&v[0];
        const float4 vhi = *(const float4*)&v[4];
        const float va = v[i1], vb = v[i2], vc = v[i3];
        const float e3s = va * vb * vc * (1.0f / 6.0f);
        const float T4 = e3s * 0.25f + a1own * vb * vc * (1.0f / 6.0f)
                       + a2own * vc * 0.5f + a3;
        a4[0] += vlo.x * T4; a4[1] += vlo.y * T4;
        a4[2] += vlo.z * T4; a4[3] += vlo.w * T4;
        a4[4] += vhi.x * T4; a4[5] += vhi.y * T4;
        a4[6] += vhi.z * T4; a4[7] += vhi.w * T4;
        a3 += e3s + (a1own * vb * 0.5f + a2own) * vc;
        a2own += vb * (0.5f * va + a1own);
        a1own += va;

        unsigned short* row = sig + ((size_t)b * TSTEPS + t) * KPAD;
        ushort8 pack;
#pragma unroll
        for (int e = 0; e < 8; ++e) pack[e] = f2bf(a4[e]);
        *(ushort8*)(row + 584 + tid * 8) = pack;                // level 4
        row[72 + tid] = f2bf(a3);                               // level 3
        if ((tid & 63) == 0) row[i1] = f2bf(a1own);             // level 1
        if ((tid & 7) == 0) row[8 + (tid >> 3)] = f2bf(a2own);  // level 2
        if (tid >= 448 && tid < 504) row[4232 + tid] = 0;       // pad
    }
}

// ---------------------------------------------------------------------------
// W fp32 [512][4680] -> bf16 [512][KPAD] (pad zeroed)
// ---------------------------------------------------------------------------
__global__ __launch_bounds__(256) void wcvt_kernel(const float* __restrict__ W,
                                                   unsigned short* __restrict__ Wb) {
    int idx = blockIdx.x * 256 + threadIdx.x;
    if (idx >= ODIM * KPAD) return;
    int n = idx / KPAD, k = idx - n * KPAD;
    Wb[idx] = (k < NSIG) ? f2bf(W[(size_t)n * NSIG + k]) : (unsigned short)0;
}

// ---------------------------------------------------------------------------
// MFMA GEMM, cross-tile software pipeline (R10).
// BM=256 x BN=128, BK=64, 8 waves (4Mx2N, each 64x64), 3 LDS buffers.
// R9 exposed 768cy of ph0 reads at each tile head (barrier ended the MFMA
// stream). R10 moves the barrier BETWEEN the two MFMA clusters and issues
// tile t+1's ph0 reads right after it, so EVERY read burst streams under an
// MFMA cluster:
//   issue N(t) reads + gloads(t+2) -> lgkm(8) -> MFMA ph0(t)
//   -> lgkm(0) [all buf(t) reads done] -> vmcnt(6) + s_barrier
//   -> issue P(t+1) reads from buf(nxt) -> MFMA ph1(t)
// Race-free with ONE barrier/tile: buf(t) reads complete before barrier(t);
// gloads(t+2) (writing slot t-1) issue after barrier(t-1). Counted vmcnt(6)
// keeps t+2's loads in flight across the barrier (never drain in loop).
// T2 XOR-swizzle (conflicts==0), XCD-grouped block swizzle, T5 setprio.
// ---------------------------------------------------------------------------
__global__ __launch_bounds__(512) void gemm_kernel(const unsigned short* __restrict__ A,
                                                   const unsigned short* __restrict__ Wb,
                                                   const float* __restrict__ bias,
                                                   float* __restrict__ out,
                                                   int Mrows) {
    __shared__ unsigned short As[3][BM * 64];   // 3 x 32 KB
    __shared__ unsigned short Bs[3][BN * 64];   // 3 x 16 KB

    const int tid = threadIdx.x;
    int nt, mt;
    if (gridDim.y == 64) {                     // full dispatch (256 blocks)
        const int li = blockIdx.y * 4 + blockIdx.x;
        const int x  = li & 7;                 // XCD (round-robin assumption)
        const int j  = li >> 3;                // 0..31 within XCD
        mt = x * 8 + (j >> 2);                 // 8 m-panels per XCD
        nt = j & 3;
    } else {
        nt = blockIdx.x; mt = blockIdx.y;
    }
    const int lane = tid & 63;
    const int wv   = tid >> 6;                 // 0..7
    const int wr   = wv >> 1;                  // 0..3 (M)
    const int wc   = wv & 1;                   // 0..1 (N)
    const int lr   = lane & 15;
    const int lq   = lane >> 4;                // 0..3
    const int sb   = lr & 7;                   // read-side swizzle key

    const f32x4 z4 = {0.0f, 0.0f, 0.0f, 0.0f};
    f32x4 acc[4][4];
#pragma unroll
    for (int i = 0; i < 4; ++i)
#pragma unroll
        for (int j = 0; j < 4; ++j) acc[i][j] = z4;

    const int srow = tid >> 3;                          // 0..63
    const int gcb  = (tid & 7) ^ (srow & 7);            // pre-swizzled src blk
    const int scol = gcb * 8;

    // per-lane global source pointers (A rows clamped for M-tail)
    const unsigned short* aptr[4];
    const unsigned short* bptr[2];
#pragma unroll
    for (int i = 0; i < 4; ++i) {
        int gr = mt * BM + i * 64 + srow;
        if (gr >= Mrows) gr = 0;
        aptr[i] = A + (size_t)gr * KPAD + scol;
    }
#pragma unroll
    for (int i = 0; i < 2; ++i)
        bptr[i] = Wb + (size_t)(nt * BN + i * 64 + srow) * KPAD + scol;

    // swizzled element columns for the two ks slices
    const int kel0 = ((lq)     ^ sb) * 8;               // ks=0: kb = lq
    const int kel1 = ((4 + lq) ^ sb) * 8;               // ks=1: kb = 4+lq

    // per-wave LDS fragment base offsets (element units)
    const int aoff = (wr * 64 + lr) * 64;               // + i*16*64
    const int boff = (wc * 64 + lr) * 64;               // + j*16*64

#define STAGE_ALL(buf, koff)                                                \
    do {                                                                    \
        _Pragma("unroll")                                                   \
        for (int i_ = 0; i_ < 4; ++i_)                                      \
            GLDS16(aptr[i_] + (koff),                                       \
                   ((char*)As[buf]) + i_ * 8192 + tid * 16);                \
        _Pragma("unroll")                                                   \
        for (int i_ = 0; i_ < 2; ++i_)                                      \
            GLDS16(bptr[i_] + (koff),                                       \
                   ((char*)Bs[buf]) + i_ * 8192 + tid * 16);                \
    } while (0)

    // prologue: tiles 0 and 1 in flight; wait tile 0 (6 of tile 1 remain)
    STAGE_ALL(0, 0);
    STAGE_ALL(1, 64);
    asm volatile("s_waitcnt vmcnt(6)" ::: "memory");
    __builtin_amdgcn_sched_barrier(0);
    __builtin_amdgcn_s_barrier();
    __builtin_amdgcn_sched_barrier(0);

    // issue ph0 reads of tile 0
    bf16x8 afP[4], bfP[4], afN[4], bfN[4];
    {
        const unsigned short* as0 = &As[0][0];
        const unsigned short* bs0 = &Bs[0][0];
#pragma unroll
        for (int i = 0; i < 4; ++i)
            afP[i] = *(const bf16x8*)&as0[aoff + i * 1024 + kel0];
#pragma unroll
        for (int j = 0; j < 4; ++j)
            bfP[j] = *(const bf16x8*)&bs0[boff + j * 1024 + kel0];
    }
    __builtin_amdgcn_sched_barrier(0);

    int cur = 0, nxt = 1, nn = 2;
    for (int t = 0; t < NKT; ++t) {
        const unsigned short* as = &As[0][0] + cur * (BM * 64);
        const unsigned short* bs = &Bs[0][0] + cur * (BN * 64);

        // ---- issue ph1(t) reads (8) + 6 gloads for t+2 ----
#pragma unroll
        for (int i = 0; i < 4; ++i)
            afN[i] = *(const bf16x8*)&as[aoff + i * 1024 + kel1];
#pragma unroll
        for (int j = 0; j < 4; ++j)
            bfN[j] = *(const bf16x8*)&bs[boff + j * 1024 + kel1];
        if (t + 2 < NKT) STAGE_ALL(nn, (t + 2) * 64);
        __builtin_amdgcn_sched_barrier(0);

        // ---- ph0 MFMA (ph1 reads stream underneath) ----
        asm volatile("s_waitcnt lgkmcnt(8)" ::: "memory");
        __builtin_amdgcn_sched_barrier(0);
        __builtin_amdgcn_s_setprio(1);
#pragma unroll
        for (int i = 0; i < 4; ++i)
#pragma unroll
            for (int j = 0; j < 4; ++j)
                acc[i][j] = __builtin_amdgcn_mfma_f32_16x16x32_bf16(
                    afP[i], bfP[j], acc[i][j], 0, 0, 0);
        __builtin_amdgcn_s_setprio(0);
        __builtin_amdgcn_sched_barrier(0);

        // ---- all buf(t) reads done; cross into tile t+1's buffer ----
        asm volatile("s_waitcnt lgkmcnt(0)" ::: "memory");
        __builtin_amdgcn_sched_barrier(0);
        if (t + 1 < NKT) {
            if (t + 2 < NKT) {
                asm volatile("s_waitcnt vmcnt(6)" ::: "memory");
            } else {
                asm volatile("s_waitcnt vmcnt(0)" ::: "memory");
            }
            __builtin_amdgcn_sched_barrier(0);
            __builtin_amdgcn_s_barrier();
            __builtin_amdgcn_sched_barrier(0);
            // issue ph0 reads of tile t+1 (stream under ph1 MFMA below)
            const unsigned short* asn = &As[0][0] + nxt * (BM * 64);
            const unsigned short* bsn = &Bs[0][0] + nxt * (BN * 64);
#pragma unroll
            for (int i = 0; i < 4; ++i)
                afP[i] = *(const bf16x8*)&asn[aoff + i * 1024 + kel0];
#pragma unroll
            for (int j = 0; j < 4; ++j)
                bfP[j] = *(const bf16x8*)&bsn[boff + j * 1024 + kel0];
            __builtin_amdgcn_sched_barrier(0);
        }

        // ---- ph1 MFMA (tile t+1's ph0 reads stream underneath) ----
        __builtin_amdgcn_s_setprio(1);
#pragma unroll
        for (int i = 0; i < 4; ++i)
#pragma unroll
            for (int j = 0; j < 4; ++j)
                acc[i][j] = __builtin_amdgcn_mfma_f32_16x16x32_bf16(
                    afN[i], bfN[j], acc[i][j], 0, 0, 0);
        __builtin_amdgcn_s_setprio(0);
        __builtin_amdgcn_sched_barrier(0);

        const int tmp = cur; cur = nxt; nxt = nn; nn = tmp;
    }

    float bn[4];
#pragma unroll
    for (int j = 0; j < 4; ++j)
        bn[j] = bias[nt * BN + wc * 64 + j * 16 + lr];

#pragma unroll
    for (int i = 0; i < 4; ++i) {
        const int mbase = mt * BM + wr * 64 + i * 16 + lq * 4;
#pragma unroll
        for (int r = 0; r < 4; ++r) {
            const int m = mbase + r;
            if (m < Mrows) {
#pragma unroll
                for (int j = 0; j < 4; ++j) {
                    const int n = nt * BN + wc * 64 + j * 16 + lr;
                    out[(size_t)m * ODIM + n] = acc[i][j][r] + bn[j];
                }
            }
        }
    }
#undef STAGE_ALL
}

extern "C" void kernel_launch(void* const* d_in, const int* in_sizes, int n_in,
                              void* d_out, int out_size, void* d_ws, size_t ws_size,
                              hipStream_t stream) {
    const float* inp  = (const float*)d_in[0];
    const float* W    = (const float*)d_in[1];
    const float* bias = (const float*)d_in[2];
    float* out = (float*)d_out;

    const size_t wbBytes = (size_t)ODIM * KPAD * sizeof(unsigned short);
    const size_t sigPB   = (size_t)TSTEPS * KPAD * sizeof(unsigned short); // 2.42 MB
    const size_t ckptPB  = (size_t)15 * NSIG * sizeof(float);              // 0.28 MB
    const size_t perB    = sigPB + ckptPB;

    int nbMax = (int)((ws_size - wbBytes) / perB);
    if (nbMax > BATCH) nbMax = BATCH;
    if (nbMax < 1) nbMax = 1;

    unsigned short* sig  = (unsigned short*)d_ws;
    float*          ckpt = (float*)((char*)d_ws + (size_t)nbMax * sigPB);
    unsigned short* Wb   = (unsigned short*)((char*)d_ws + (ws_size - wbBytes));

    wcvt_kernel<<<(ODIM * KPAD + 255) / 256, 256, 0, stream>>>(W, Wb);

    for (int b0 = 0; b0 < BATCH; b0 += nbMax) {
        const int nb = (b0 + nbMax <= BATCH) ? nbMax : (BATCH - b0);
        const int Mrows = nb * TSTEPS;
        const float* ipb = inp + (size_t)b0 * LSEQ * CIN;
        sig_ckpt_kernel<<<nb, 512, 0, stream>>>(ipb, ckpt);
        sig_write_kernel<<<dim3(NCHUNK, nb), 512, 0, stream>>>(ipb, ckpt, sig);
        gemm_kernel<<<dim3(ODIM / BN, (Mrows + BM - 1) / BM), 512, 0, stream>>>(
            sig, Wb, bias, out + (size_t)b0 * TSTEPS * ODIM, Mrows);
    }
}

// Round 11
// 147.704 us; speedup vs baseline: 1.1969x; 1.0052x over previous
//
#include <hip/hip_runtime.h>
#include <hip/hip_bf16.h>

// Problem constants (QREncoder: path signature depth 4 + linear head)
#define BATCH 64
#define LSEQ 256
#define CIN 7
#define CC 8           // channels incl. time
#define NSIG 4680      // 8 + 64 + 512 + 4096
#define KPAD 4736      // NSIG padded to multiple of 64
#define TSTEPS 255     // LSEQ - 1
#define ODIM 512
#define NCHUNK 16      // time chunks for sig write parallelism
#define CH 16          // steps per chunk (last chunk: 15)
#define NKT 74         // KPAD / 64 K-steps
#define BM 256
#define BN 128
#define WCVT_BLK 592   // ODIM*KPAD/8/512

typedef __attribute__((ext_vector_type(8))) unsigned short ushort8;
typedef __attribute__((ext_vector_type(8))) __bf16 bf16x8;
typedef __attribute__((ext_vector_type(4))) float f32x4;

__device__ __forceinline__ unsigned short f2bf(float x) {
    __hip_bfloat16 h = __float2bfloat16(x);   // RNE
    return *(unsigned short*)&h;
}

#define GLDS16(gp, lp)                                                      \
    __builtin_amdgcn_global_load_lds(                                       \
        (const __attribute__((address_space(1))) void*)(gp),                \
        (__attribute__((address_space(3))) void*)(lp), 16, 0, 0)

// ---------------------------------------------------------------------------
// prep kernel: scan-checkpoint part (4 blocks/batch) + W conversion part.
// Scan: block (b, q=bx&3) owns a4 elements for owners o in [128q, 128q+128);
// thread = (o, e2): carries a1[i1], a2[i1,i2], a3[o], a4[8o+e2], a4[8o+e2+4]
// (~19 VALU/step vs 35 of the 8-elem variant). All blocks replay the cheap
// a1/a2/a3 chain for their owners; checkpoint regions are disjoint.
// Wcvt: remaining blocks convert W fp32 -> bf16 [512][KPAD] vectorized
// (float4 x2 -> ushort8), pad zeroed. Rides the otherwise-idle CUs.
// ---------------------------------------------------------------------------
__global__ __launch_bounds__(512) void prep_kernel(const float* __restrict__ inp,
                                                   float* __restrict__ ckpt,
                                                   const float* __restrict__ W,
                                                   unsigned short* __restrict__ Wb,
                                                   int nb) {
    __shared__ float sDx[TSTEPS * CC];
    const int bx  = blockIdx.x;
    const int tid = threadIdx.x;

    if (bx < 4 * nb) {
        const int b = bx >> 2, q = bx & 3;
        const float* ip = inp + (size_t)b * LSEQ * CIN;
        for (int i = tid; i < TSTEPS * CC; i += 512) {
            int t = i >> 3, c = i & 7;
            sDx[i] = (c == 0) ? (1.0f / 255.0f)
                              : ip[(t + 1) * CIN + (c - 1)] - ip[t * CIN + (c - 1)];
        }
        __syncthreads();

        const int o  = q * 128 + (tid >> 2);
        const int e2 = tid & 3;
        const int i1 = o >> 6, i2 = (o >> 3) & 7, i3 = o & 7;
        float a1 = 0.0f, a2 = 0.0f, a3 = 0.0f, a4a = 0.0f, a4b = 0.0f;

        for (int t = 0; t < 240; ++t) {
            const float* v = &sDx[t * CC];
            const float va = v[i1], vb = v[i2], vc = v[i3];
            const float vA = v[e2], vB = v[e2 + 4];
            const float e3s = va * vb * vc * (1.0f / 6.0f);
            const float T4 = e3s * 0.25f + a1 * vb * vc * (1.0f / 6.0f)
                           + a2 * vc * 0.5f + a3;
            a4a += vA * T4;
            a4b += vB * T4;
            a3 += e3s + (a1 * vb * 0.5f + a2) * vc;
            a2 += vb * (0.5f * va + a1);
            a1 += va;

            if (((t + 1) & 15) == 0) {
                const int c = ((t + 1) >> 4) - 1;   // 0..14
                float* cp = ckpt + ((size_t)b * 15 + c) * NSIG;
                cp[584 + o * 8 + e2]     = a4a;
                cp[584 + o * 8 + e2 + 4] = a4b;
                if (e2 == 0) {
                    cp[72 + o] = a3;
                    if ((o & 7) == 0)  cp[8 + (o >> 3)] = a2;
                    if ((o & 63) == 0) cp[i1] = a1;
                }
            }
        }
    } else {
        const int vid = (bx - 4 * nb) * 512 + tid;
        if (vid < ODIM * (KPAD / 8)) {
            const int n = vid / (KPAD / 8);
            const int g = vid - n * (KPAD / 8);
            ushort8 pk;
            if (g < NSIG / 8) {
                const float* wp = W + (size_t)n * NSIG + g * 8;
                float4 f0 = *(const float4*)wp;
                float4 f1 = *(const float4*)(wp + 4);
                pk[0] = f2bf(f0.x); pk[1] = f2bf(f0.y);
                pk[2] = f2bf(f0.z); pk[3] = f2bf(f0.w);
                pk[4] = f2bf(f1.x); pk[5] = f2bf(f1.y);
                pk[6] = f2bf(f1.z); pk[7] = f2bf(f1.w);
            } else {
#pragma unroll
                for (int e = 0; e < 8; ++e) pk[e] = 0;
            }
            *(ushort8*)(Wb + (size_t)n * KPAD + g * 8) = pk;
        }
    }
}

// ---------------------------------------------------------------------------
// Scan pass B: grid (NCHUNK, nb). Block (chunk,b) loads the chunk's start
// state from ckpt (chunk 0: zeros), runs <=16 steps, writes sig rows (bf16).
// ---------------------------------------------------------------------------
__global__ __launch_bounds__(512) void sig_write_kernel(const float* __restrict__ inp,
                                                        const float* __restrict__ ckpt,
                                                        unsigned short* __restrict__ sig) {
    __shared__ float sDx[CH * CC];

    const int chunk = blockIdx.x;
    const int b     = blockIdx.y;
    const int tid   = threadIdx.x;
    const int t0    = chunk * CH;
    const int t1    = (chunk == NCHUNK - 1) ? TSTEPS : t0 + CH;

    const float* ip = inp + (size_t)b * LSEQ * CIN;
    for (int i = tid; i < (t1 - t0) * CC; i += 512) {
        int t = t0 + (i >> 3), c = i & 7;
        sDx[i] = (c == 0) ? (1.0f / 255.0f)
                          : ip[(t + 1) * CIN + (c - 1)] - ip[t * CIN + (c - 1)];
    }
    __syncthreads();

    const int i1 = tid >> 6;
    const int i2 = (tid >> 3) & 7;
    const int i3 = tid & 7;

    float a1own, a2own, a3;
    float a4[8];
    if (chunk == 0) {
        a1own = a2own = a3 = 0.0f;
#pragma unroll
        for (int e = 0; e < 8; ++e) a4[e] = 0.0f;
    } else {
        const float* cp = ckpt + ((size_t)b * 15 + (chunk - 1)) * NSIG;
        a1own = cp[i1];
        a2own = cp[8 + (tid >> 3)];
        a3    = cp[72 + tid];
        float4 q0 = *(const float4*)&cp[584 + tid * 8];
        float4 q1 = *(const float4*)&cp[584 + tid * 8 + 4];
        a4[0] = q0.x; a4[1] = q0.y; a4[2] = q0.z; a4[3] = q0.w;
        a4[4] = q1.x; a4[5] = q1.y; a4[6] = q1.z; a4[7] = q1.w;
    }

    for (int t = t0; t < t1; ++t) {
        const float* v = &sDx[(t - t0) * CC];
        const float4 vlo = *(const float4*)&v[0];
        const float4 vhi = *(const float4*)&v[4];
        const float va = v[i1], vb = v[i2], vc = v[i3];
        const float e3s = va * vb * vc * (1.0f / 6.0f);
        const float T4 = e3s * 0.25f + a1own * vb * vc * (1.0f / 6.0f)
                       + a2own * vc * 0.5f + a3;
        a4[0] += vlo.x * T4; a4[1] += vlo.y * T4;
        a4[2] += vlo.z * T4; a4[3] += vlo.w * T4;
        a4[4] += vhi.x * T4; a4[5] += vhi.y * T4;
        a4[6] += vhi.z * T4; a4[7] += vhi.w * T4;
        a3 += e3s + (a1own * vb * 0.5f + a2own) * vc;
        a2own += vb * (0.5f * va + a1own);
        a1own += va;

        unsigned short* row = sig + ((size_t)b * TSTEPS + t) * KPAD;
        ushort8 pack;
#pragma unroll
        for (int e = 0; e < 8; ++e) pack[e] = f2bf(a4[e]);
        *(ushort8*)(row + 584 + tid * 8) = pack;                // level 4
        row[72 + tid] = f2bf(a3);                               // level 3
        if ((tid & 63) == 0) row[i1] = f2bf(a1own);             // level 1
        if ((tid & 7) == 0) row[8 + (tid >> 3)] = f2bf(a2own);  // level 2
        if (tid >= 448 && tid < 504) row[4232 + tid] = 0;       // pad
    }
}

// ---------------------------------------------------------------------------
// MFMA GEMM, cross-tile pipeline with STATIC buffer indices (R11).
// Same schedule as R10 (every ds_read burst streams under an MFMA cluster,
// one barrier/tile, counted vmcnt(6)); the K-loop is unrolled x3 so the
// 3 LDS buffer bases are compile-time constants -> ds_read offsets fold to
// immediates, buffer-swap & address VALU disappears (R10: VALUBusy 20%
// ~= the 490cy/tile gap to the LDS-pipe model).
// ---------------------------------------------------------------------------
__global__ __launch_bounds__(512) void gemm_kernel(const unsigned short* __restrict__ A,
                                                   const unsigned short* __restrict__ Wb,
                                                   const float* __restrict__ bias,
                                                   float* __restrict__ out,
                                                   int Mrows) {
    __shared__ unsigned short As[3][BM * 64];   // 3 x 32 KB
    __shared__ unsigned short Bs[3][BN * 64];   // 3 x 16 KB

    const int tid = threadIdx.x;
    int nt, mt;
    if (gridDim.y == 64) {                     // full dispatch (256 blocks)
        const int li = blockIdx.y * 4 + blockIdx.x;
        const int x  = li & 7;                 // XCD (round-robin assumption)
        const int j  = li >> 3;                // 0..31 within XCD
        mt = x * 8 + (j >> 2);                 // 8 m-panels per XCD
        nt = j & 3;
    } else {
        nt = blockIdx.x; mt = blockIdx.y;
    }
    const int lane = tid & 63;
    const int wv   = tid >> 6;                 // 0..7
    const int wr   = wv >> 1;                  // 0..3 (M)
    const int wc   = wv & 1;                   // 0..1 (N)
    const int lr   = lane & 15;
    const int lq   = lane >> 4;                // 0..3
    const int sb   = lr & 7;                   // read-side swizzle key

    const f32x4 z4 = {0.0f, 0.0f, 0.0f, 0.0f};
    f32x4 acc[4][4];
#pragma unroll
    for (int i = 0; i < 4; ++i)
#pragma unroll
        for (int j = 0; j < 4; ++j) acc[i][j] = z4;

    const int srow = tid >> 3;                          // 0..63
    const int gcb  = (tid & 7) ^ (srow & 7);            // pre-swizzled src blk
    const int scol = gcb * 8;

    const unsigned short* aptr[4];
    const unsigned short* bptr[2];
#pragma unroll
    for (int i = 0; i < 4; ++i) {
        int gr = mt * BM + i * 64 + srow;
        if (gr >= Mrows) gr = 0;
        aptr[i] = A + (size_t)gr * KPAD + scol;
    }
#pragma unroll
    for (int i = 0; i < 2; ++i)
        bptr[i] = Wb + (size_t)(nt * BN + i * 64 + srow) * KPAD + scol;

    const int kel0 = ((lq)     ^ sb) * 8;               // ks=0 swizzled col
    const int kel1 = ((4 + lq) ^ sb) * 8;               // ks=1 swizzled col
    const int aoff = (wr * 64 + lr) * 64;
    const int boff = (wc * 64 + lr) * 64;

#define STAGE_ALL(BUF, koff)                                                \
    do {                                                                    \
        _Pragma("unroll")                                                   \
        for (int i_ = 0; i_ < 4; ++i_)                                      \
            GLDS16(aptr[i_] + (koff),                                       \
                   ((char*)As[BUF]) + i_ * 8192 + tid * 16);                \
        _Pragma("unroll")                                                   \
        for (int i_ = 0; i_ < 2; ++i_)                                      \
            GLDS16(bptr[i_] + (koff),                                       \
                   ((char*)Bs[BUF]) + i_ * 8192 + tid * 16);                \
    } while (0)

#define MFMA16(AF, BF)                                                      \
    do {                                                                    \
        _Pragma("unroll")                                                   \
        for (int im_ = 0; im_ < 4; ++im_)                                   \
            _Pragma("unroll")                                               \
            for (int jm_ = 0; jm_ < 4; ++jm_)                               \
                acc[im_][jm_] = __builtin_amdgcn_mfma_f32_16x16x32_bf16(    \
                    AF[im_], BF[jm_], acc[im_][jm_], 0, 0, 0);              \
    } while (0)

#define LDF(DST, SRC, BASE, KEL)                                            \
    do {                                                                    \
        _Pragma("unroll")                                                   \
        for (int l_ = 0; l_ < 4; ++l_)                                      \
            DST[l_] = *(const bf16x8*)&SRC[(BASE) + l_ * 1024 + (KEL)];     \
    } while (0)

    bf16x8 afP[4], bfP[4], afN[4], bfN[4];

    // prologue: tiles 0,1 in flight; wait tile 0 (6 of tile 1 remain)
    STAGE_ALL(0, 0);
    STAGE_ALL(1, 64);
    asm volatile("s_waitcnt vmcnt(6)" ::: "memory");
    __builtin_amdgcn_sched_barrier(0);
    __builtin_amdgcn_s_barrier();
    __builtin_amdgcn_sched_barrier(0);
    LDF(afP, (&As[0][0]), aoff, kel0);
    LDF(bfP, (&Bs[0][0]), boff, kel0);
    __builtin_amdgcn_sched_barrier(0);

    int koff = 128;   // global K offset of tile t+2

#define TILE_FULL(CUR, NXT, NN)                                             \
    {                                                                       \
        LDF(afN, (&As[CUR][0]), aoff, kel1);                                \
        LDF(bfN, (&Bs[CUR][0]), boff, kel1);                                \
        STAGE_ALL(NN, koff);                                                \
        koff += 64;                                                         \
        __builtin_amdgcn_sched_barrier(0);                                  \
        asm volatile("s_waitcnt lgkmcnt(8)" ::: "memory");                  \
        __builtin_amdgcn_sched_barrier(0);                                  \
        __builtin_amdgcn_s_setprio(1);                                      \
        MFMA16(afP, bfP);                                                   \
        __builtin_amdgcn_s_setprio(0);                                      \
        __builtin_amdgcn_sched_barrier(0);                                  \
        asm volatile("s_waitcnt lgkmcnt(0)" ::: "memory");                  \
        __builtin_amdgcn_sched_barrier(0);                                  \
        asm volatile("s_waitcnt vmcnt(6)" ::: "memory");                    \
        __builtin_amdgcn_sched_barrier(0);                                  \
        __builtin_amdgcn_s_barrier();                                       \
        __builtin_amdgcn_sched_barrier(0);                                  \
        LDF(afP, (&As[NXT][0]), aoff, kel0);                                \
        LDF(bfP, (&Bs[NXT][0]), boff, kel0);                                \
        __builtin_amdgcn_sched_barrier(0);                                  \
        __builtin_amdgcn_s_setprio(1);                                      \
        MFMA16(afN, bfN);                                                   \
        __builtin_amdgcn_s_setprio(0);                                      \
        __builtin_amdgcn_sched_barrier(0);                                  \
    }

    for (int tb = 0; tb < 24; ++tb) {          // tiles 0..71
        TILE_FULL(0, 1, 2);
        TILE_FULL(1, 2, 0);
        TILE_FULL(2, 0, 1);
    }

    {   // tile 72 (buf 0): no staging; drain remaining loads for tile 73
        LDF(afN, (&As[0][0]), aoff, kel1);
        LDF(bfN, (&Bs[0][0]), boff, kel1);
        __builtin_amdgcn_sched_barrier(0);
        asm volatile("s_waitcnt lgkmcnt(8)" ::: "memory");
        __builtin_amdgcn_sched_barrier(0);
        __builtin_amdgcn_s_setprio(1);
        MFMA16(afP, bfP);
        __builtin_amdgcn_s_setprio(0);
        __builtin_amdgcn_sched_barrier(0);
        asm volatile("s_waitcnt lgkmcnt(0)" ::: "memory");
        __builtin_amdgcn_sched_barrier(0);
        asm volatile("s_waitcnt vmcnt(0)" ::: "memory");
        __builtin_amdgcn_sched_barrier(0);
        __builtin_amdgcn_s_barrier();
        __builtin_amdgcn_sched_barrier(0);
        LDF(afP, (&As[1][0]), aoff, kel0);
        LDF(bfP, (&Bs[1][0]), boff, kel0);
        __builtin_amdgcn_sched_barrier(0);
        __builtin_amdgcn_s_setprio(1);
        MFMA16(afN, bfN);
        __builtin_amdgcn_s_setprio(0);
        __builtin_amdgcn_sched_barrier(0);
    }
    {   // tile 73 (buf 1): last
        LDF(afN, (&As[1][0]), aoff, kel1);
        LDF(bfN, (&Bs[1][0]), boff, kel1);
        __builtin_amdgcn_sched_barrier(0);
        asm volatile("s_waitcnt lgkmcnt(8)" ::: "memory");
        __builtin_amdgcn_sched_barrier(0);
        __builtin_amdgcn_s_setprio(1);
        MFMA16(afP, bfP);
        __builtin_amdgcn_s_setprio(0);
        __builtin_amdgcn_sched_barrier(0);
        asm volatile("s_waitcnt lgkmcnt(0)" ::: "memory");
        __builtin_amdgcn_sched_barrier(0);
        __builtin_amdgcn_s_setprio(1);
        MFMA16(afN, bfN);
        __builtin_amdgcn_s_setprio(0);
        __builtin_amdgcn_sched_barrier(0);
    }

    float bn[4];
#pragma unroll
    for (int j = 0; j < 4; ++j)
        bn[j] = bias[nt * BN + wc * 64 + j * 16 + lr];

#pragma unroll
    for (int i = 0; i < 4; ++i) {
        const int mbase = mt * BM + wr * 64 + i * 16 + lq * 4;
#pragma unroll
        for (int r = 0; r < 4; ++r) {
            const int m = mbase + r;
            if (m < Mrows) {
#pragma unroll
                for (int j = 0; j < 4; ++j) {
                    const int n = nt * BN + wc * 64 + j * 16 + lr;
                    out[(size_t)m * ODIM + n] = acc[i][j][r] + bn[j];
                }
            }
        }
    }
#undef STAGE_ALL
#undef MFMA16
#undef LDF
#undef TILE_FULL
}

extern "C" void kernel_launch(void* const* d_in, const int* in_sizes, int n_in,
                              void* d_out, int out_size, void* d_ws, size_t ws_size,
                              hipStream_t stream) {
    const float* inp  = (const float*)d_in[0];
    const float* W    = (const float*)d_in[1];
    const float* bias = (const float*)d_in[2];
    float* out = (float*)d_out;

    const size_t wbBytes = (size_t)ODIM * KPAD * sizeof(unsigned short);
    const size_t sigPB   = (size_t)TSTEPS * KPAD * sizeof(unsigned short); // 2.42 MB
    const size_t ckptPB  = (size_t)15 * NSIG * sizeof(float);              // 0.28 MB
    const size_t perB    = sigPB + ckptPB;

    int nbMax = (int)((ws_size - wbBytes) / perB);
    if (nbMax > BATCH) nbMax = BATCH;
    if (nbMax < 1) nbMax = 1;

    unsigned short* sig  = (unsigned short*)d_ws;
    float*          ckpt = (float*)((char*)d_ws + (size_t)nbMax * sigPB);
    unsigned short* Wb   = (unsigned short*)((char*)d_ws + (ws_size - wbBytes));

    for (int b0 = 0; b0 < BATCH; b0 += nbMax) {
        const int nb = (b0 + nbMax <= BATCH) ? nbMax : (BATCH - b0);
        const int Mrows = nb * TSTEPS;
        const float* ipb = inp + (size_t)b0 * LSEQ * CIN;
        prep_kernel<<<4 * nb + WCVT_BLK, 512, 0, stream>>>(ipb, ckpt, W, Wb, nb);
        sig_write_kernel<<<dim3(NCHUNK, nb), 512, 0, stream>>>(ipb, ckpt, sig);
        gemm_kernel<<<dim3(ODIM / BN, (Mrows + BM - 1) / BM), 512, 0, stream>>>(
            sig, Wb, bias, out + (size_t)b0 * TSTEPS * ODIM, Mrows);
    }
}